// Round 14
// baseline (163.989 us; speedup 1.0000x reference)
//
#include <hip/hip_runtime.h>
#include <hip/hip_bf16.h>

typedef unsigned short u16;
typedef unsigned int   u32;
typedef __attribute__((ext_vector_type(2))) float f32x2;
typedef __attribute__((ext_vector_type(4))) float f32x4;
typedef __attribute__((ext_vector_type(4))) u32   u32x4;
typedef __attribute__((ext_vector_type(8))) short bf16x8;

#define HWPIX  9216
#define NPIX   73728
#define LN_EPS 1e-5f
#define MROW   64       // pixels per block
#define ASTR   40       // afg chunk row stride (elems): 32 + 8 pad

template<int N> struct IC { static constexpr int value = N; };

__device__ __forceinline__ u16 f2bf(float f){
  u32 u = __builtin_bit_cast(u32, f);
  u += 0x7fffu + ((u >> 16) & 1u);          // RTNE
  return (u16)(u >> 16);
}
__device__ __forceinline__ u32 pkbf(float lo, float hi){   // 1 inst packed cvt
  u32 d;
  asm("v_cvt_pk_bf16_f32 %0, %1, %2" : "=v"(d) : "v"(lo), "v"(hi));
  return d;
}
__device__ __forceinline__ float bfu2f(u16 h){ return __builtin_bit_cast(float, (u32)h << 16); }
__device__ __forceinline__ float fsigmoid(float v){ return __fdividef(1.f, 1.f + __expf(-v)); }
__device__ __forceinline__ float fsilu(float v){ return __fdividef(v, 1.f + __expf(-v)); }

__device__ __forceinline__ void gld16(const u16* g, u16* l){
  __builtin_amdgcn_global_load_lds((const __attribute__((address_space(1))) void*)g,
                                   (__attribute__((address_space(3))) void*)l,
                                   16, 0, 0);
}

// ---------------- kernel 1: weight convert (dot interleaved by window + gate) ------
// wsdot chunk c: window w = c>>1, shift s = (c&1)+1. dot s1 = pk rows 0..255,
// dot s2 = pk rows 512..767. Slot S layout identical to r13 (XOR bank swizzle).
__global__ __launch_bounds__(256) void wconv(const float* __restrict__ pk,
                                             const float* __restrict__ gk,
                                             u16* __restrict__ wsdot,   // 16 chunks
                                             u16* __restrict__ wsgate)  // 16 chunks
{
  int gid = blockIdx.x * 256 + threadIdx.x;   // 32768 = 128 blocks
  int t = gid >> 10, S = gid & 1023;
  int q = (S >> 2) & 15, pp = S & 3, w8 = (S >> 6) & 7, rb = S >> 9;
  int n  = rb * 128 + w8 * 16 + q;
  int kq = pp ^ ((q >> 1) & 3);
  const float* W; int k0; u16* dst;
  if (t < 16) { W = pk; k0 = (t & 1) * 512 + (t >> 1) * 32 + kq * 8; dst = wsdot + (size_t)t * 8192; }
  else        { W = gk; k0 = (t - 16) * 32 + kq * 8;                 dst = wsgate + (size_t)(t - 16) * 8192; }
  u32 ow[4];
  #pragma unroll
  for (int e = 0; e < 4; ++e) {
    float f0 = W[(size_t)(k0 + 2*e)     * 256 + n];
    float f1 = W[(size_t)(k0 + 2*e + 1) * 256 + n];
    ow[e] = (u32)f2bf(f0) | ((u32)f2bf(f1) << 16);
  }
  *(u32x4*)(dst + (size_t)S * 8) = (u32x4){ow[0], ow[1], ow[2], ow[3]};
}

// ---------------- kernel 2: per-pixel LN stats + per-(b,h) partial sums ------------
__global__ __launch_bounds__(256) void prep(const float* __restrict__ x,
                                            const float* __restrict__ g,
                                            const float* __restrict__ bt,
                                            float* __restrict__ mu_rs,
                                            float* __restrict__ partial)
{
  const int bh = blockIdx.x;
  const int tid = threadIdx.x;
  const int wv = tid >> 6, lane = tid & 63;
  const float* xrow = x + (size_t)bh * 96 * 256;
  __shared__ float red[4][256];

  f32x4 gv = *(const f32x4*)(g  + lane * 4);
  f32x4 bv = *(const f32x4*)(bt + lane * 4);
  f32x4 acc = {0.f, 0.f, 0.f, 0.f};

  for (int w = wv; w < 96; w += 4) {
    f32x4 v = *(const f32x4*)(xrow + w * 256 + lane * 4);
    float s  = v[0] + v[1] + v[2] + v[3];
    float s2 = v[0]*v[0] + v[1]*v[1] + v[2]*v[2] + v[3]*v[3];
    #pragma unroll
    for (int m = 1; m < 64; m <<= 1) { s += __shfl_xor(s, m); s2 += __shfl_xor(s2, m); }
    float mu  = s * (1.f / 256.f);
    float var = s2 * (1.f / 256.f) - mu * mu;
    float rs  = rsqrtf(var + LN_EPS);
    if (lane == 0) *(f32x2*)(mu_rs + (size_t)(bh * 96 + w) * 2) = f32x2{mu, rs};
    #pragma unroll
    for (int j = 0; j < 4; ++j) acc[j] += (v[j] - mu) * rs * gv[j] + bv[j];
  }
  *(f32x4*)(&red[wv][lane * 4]) = acc;
  __syncthreads();
  float s = red[0][tid] + red[1][tid] + red[2][tid] + red[3][tid];
  partial[(size_t)bh * 256 + tid] = s;
}

// ---------------- kernel 3: reduce rows -> spatial mean [8][258] (wrap-padded) -----
__global__ __launch_bounds__(256) void ln_mean(const float* __restrict__ partial,
                                               float* __restrict__ mean)
{
  int b = blockIdx.x, c = threadIdx.x;
  float s = 0.f;
  for (int h = 0; h < 96; ++h) s += partial[((size_t)b * 96 + h) * 256 + c];
  float m = s * (1.f / 9216.f);
  mean[b * 258 + c] = m;
  if (c < 2) mean[b * 258 + 256 + c] = m;
}

// ---------------- kernel 4: fold wedge into per-batch weights (r10-validated) ------
__global__ __launch_bounds__(256) void wfold(const float* __restrict__ pk,
                                             const float* __restrict__ meang,
                                             u16* __restrict__ wsW)
{
  __shared__ float msh[256];
  int gid = blockIdx.x * 256 + threadIdx.x;   // 65536 = 256 blocks
  int chunk = gid >> 10;
  int b = chunk >> 3, j = chunk & 7;
  msh[threadIdx.x] = meang[b * 258 + threadIdx.x];
  __syncthreads();
  int S = gid & 1023;
  int q = (S >> 2) & 15, pp = S & 3, w8 = (S >> 6) & 7, rb = S >> 9;
  int n  = rb * 128 + w8 * 16 + q;
  int kq = pp ^ ((q >> 1) & 3);
  u32 ow[4];
  #pragma unroll
  for (int e = 0; e < 4; ++e) {
    float r[2];
    #pragma unroll
    for (int hh = 0; hh < 2; ++hh) {
      int c = j * 32 + kq * 8 + 2 * e + hh;
      int cm1 = (c + 255) & 255, cm2 = (c + 254) & 255;
      int cp1 = (c + 1) & 255,   cp2 = (c + 2) & 255;
      r[hh] = msh[cm1] * pk[(size_t)(256 + cm1) * 256 + n]
            - msh[cp1] * pk[(size_t)(256 + c)   * 256 + n]
            + msh[cm2] * pk[(size_t)(768 + cm2) * 256 + n]
            - msh[cp2] * pk[(size_t)(768 + c)   * 256 + n];
    }
    ow[e] = (u32)f2bf(r[0]) | ((u32)f2bf(r[1]) << 16);
  }
  *(u32x4*)(wsW + (size_t)chunk * 8192 + (size_t)S * 8) = (u32x4){ow[0], ow[1], ow[2], ow[3]};
}

// ---------------- kernel 5: fused main ---------------------------------------------
// Window-major schedule, 32 steps: per window w: {dotS1, dotS2, h-double}.
// h0..h5 computed ONCE per window (registers, reused by 3 builds). h-step does TWO
// MFMA bursts (accG += h@W', accA += h@Wg_h). Depth-4 B DMA ring, counted vmcnt.
__global__ __launch_bounds__(512, 2) void fused(
    const float* __restrict__ x,
    const float* __restrict__ lng, const float* __restrict__ lnb,
    const u16* __restrict__ wsdot, const u16* __restrict__ wsW,
    const u16* __restrict__ wsgate, const float* __restrict__ mu_rs,
    const float* __restrict__ pbias, const float* __restrict__ gbias,
    const float* __restrict__ gamma, const float* __restrict__ meang,
    float* __restrict__ out)
{
  __shared__ u16 afg[2][MROW * ASTR];   // 10240 B  A chunk dbuf
  __shared__ u16 Bl [4][8192];          // 65536 B  B DMA ring (depth 4)
  __shared__ float gshb[2][260];        //  2080 B  ln gamma/beta (wrap-padded 4)
  __shared__ float msh[258];            //  1032 B  spatial mean (wrap-padded)
  __shared__ float mursh[128];          //   512 B  per-row {mu, rs}   (total 79400 B)

  const int tid  = threadIdx.x;
  const long pix0 = (long)blockIdx.x * MROW;
  const int bat  = (int)(pix0 / HWPIX);      // 9216 % 64 == 0

  const int wave = tid >> 6, lane = tid & 63;
  const int wr = wave & 1, wc = wave >> 1;       // 2x4 wave grid
  const int fr = lane & 15, kq = lane >> 4;
  const int bswz = (kq ^ ((fr >> 1) & 3)) * 8;
  const int brow = tid >> 3, o4 = (tid & 7) * 4; // A-build: row, 4-ch slice

  // stage chunk q -> ring slot q&3. q<32: window phase (w=q>>2; r: 0=dotS1, 1=dotS2,
  // 2=W', 3=WgH). q>=32: WgGF chunk (wsgate 8..15).
  auto stageQ = [&](auto QC) {
    constexpr int q = decltype(QC)::value;
    constexpr int sl = q & 3;
    const u16* base;
    if constexpr (q < 32) {
      constexpr int w = q >> 2, r = q & 3;
      if constexpr      (r == 0) base = wsdot  + (size_t)(2 * w)     * 8192;
      else if constexpr (r == 1) base = wsdot  + (size_t)(2 * w + 1) * 8192;
      else if constexpr (r == 2) base = wsW + (size_t)bat * 65536 + (size_t)w * 8192;
      else                       base = wsgate + (size_t)w * 8192;
    } else {
      base = wsgate + (size_t)(q - 24) * 8192;   // WgGF chunks 8..15
    }
    const u16* src = base + tid * 8;
    u16* dst = &Bl[sl][wave * 512];              // wave-uniform base; HW adds lane*16B
    gld16(src, dst);
    gld16(src + 4096, dst + 4096);
  };

  stageQ(IC<0>{});
  stageQ(IC<1>{});

  // ---- table fill ----
  if (tid < 256)      { gshb[0][tid] = lng[tid]; gshb[1][tid] = lnb[tid]; }
  else if (tid < 260) { int c = tid - 256; gshb[0][256 + c] = lng[c]; gshb[1][256 + c] = lnb[c]; }
  if (tid < 258) msh[tid] = meang[bat * 258 + tid];
  if (tid < 128) mursh[tid] = mu_rs[pix0 * 2 + tid];

  f32x4 accG[2][4], accA[2][4];
  #pragma unroll
  for (int i = 0; i < 2; ++i)
    #pragma unroll
    for (int j = 0; j < 4; ++j) { accG[i][j] = (f32x4){0,0,0,0}; accA[i][j] = (f32x4){0,0,0,0}; }
  u32 gfp[2][4][2];
  float pbv[4];
  #pragma unroll
  for (int nt = 0; nt < 4; ++nt) pbv[nt] = pbias[wc * 64 + nt * 16 + fr];

  __syncthreads();                    // tables + stage(q0,q1) drained (prologue only)

  const float* xrowp = x + (pix0 + brow) * 256;
  const float muv = mursh[brow * 2];
  const float rsv = mursh[brow * 2 + 1];

  // h window registers: computed once per window, reused by 3 builds
  float h0, h1, h2, h3, h4, h5;
  auto computeH = [&](int w) {
    const int cc = w * 32 + o4;
    f32x4 xa = *(const f32x4*)(xrowp + cc);
    f32x2 xb = (cc == 252) ? f32x2{xrowp[0], xrowp[1]}
                           : *(const f32x2*)(xrowp + cc + 4);
    h0 = (xa[0] - muv) * rsv * gshb[0][cc]     + gshb[1][cc];
    h1 = (xa[1] - muv) * rsv * gshb[0][cc + 1] + gshb[1][cc + 1];
    h2 = (xa[2] - muv) * rsv * gshb[0][cc + 2] + gshb[1][cc + 2];
    h3 = (xa[3] - muv) * rsv * gshb[0][cc + 3] + gshb[1][cc + 3];
    h4 = (xb[0] - muv) * rsv * gshb[0][cc + 4] + gshb[1][cc + 4];
    h5 = (xb[1] - muv) * rsv * gshb[0][cc + 5] + gshb[1][cc + 5];
  };
  auto buildDot = [&](auto SC, int w, int buf) {
    constexpr int s = decltype(SC)::value;
    const int cc = w * 32 + o4;
    float a0, a1, a2, a3;
    if constexpr (s == 1) { a0 = h1; a1 = h2; a2 = h3; a3 = h4; }
    else                  { a0 = h2; a1 = h3; a2 = h4; a3 = h5; }
    float r0 = fsilu(h0 * (a0 - msh[cc + s]));
    float r1 = fsilu(h1 * (a1 - msh[cc + 1 + s]));
    float r2 = fsilu(h2 * (a2 - msh[cc + 2 + s]));
    float r3 = fsilu(h3 * (a3 - msh[cc + 3 + s]));
    *(u32*)(&afg[buf][brow * ASTR + o4])     = pkbf(r0, r1);
    *(u32*)(&afg[buf][brow * ASTR + o4 + 2]) = pkbf(r2, r3);
  };
  auto buildH = [&](int buf) {
    *(u32*)(&afg[buf][brow * ASTR + o4])     = pkbf(h0, h1);
    *(u32*)(&afg[buf][brow * ASTR + o4 + 2]) = pkbf(h2, h3);
  };
  auto gfcopy = [&](auto CGC, int buf) {
    constexpr int cg = decltype(CGC)::value;
    constexpr int par = cg & 1;
    if (wc == (cg >> 1)) {
      #pragma unroll
      for (int v = 0; v < 2; ++v) {
        #pragma unroll
        for (int ai = 0; ai < 2; ++ai)
          #pragma unroll
          for (int rp = 0; rp < 2; ++rp) {
            u32 pw = gfp[ai][par * 2 + v][rp];
            int row0 = wr * 32 + ai * 16 + kq * 4 + rp * 2;
            afg[buf][row0 * ASTR + v * 16 + fr]       = (u16)pw;
            afg[buf][(row0 + 1) * ASTR + v * 16 + fr] = (u16)(pw >> 16);
          }
      }
    }
  };

  auto mfma_into = [&](f32x4 (&ac)[2][4], int abuf, const u16* bp) {
    const u16* ar = &afg[abuf][(wr * 32 + fr) * ASTR + kq * 8];
    bf16x8 av0 = *(const bf16x8*)(ar);
    bf16x8 av1 = *(const bf16x8*)(ar + 16 * ASTR);
    __builtin_amdgcn_s_setprio(1);
    #pragma unroll
    for (int nt = 0; nt < 4; ++nt) {
      bf16x8 bv = *(const bf16x8*)(bp + nt * 512);
      ac[0][nt] = __builtin_amdgcn_mfma_f32_16x16x32_bf16(av0, bv, ac[0][nt], 0, 0, 0);
      ac[1][nt] = __builtin_amdgcn_mfma_f32_16x16x32_bf16(av1, bv, ac[1][nt], 0, 0, 0);
    }
    __builtin_amdgcn_s_setprio(0);
  };

  // prologue: build chunk 0 (h(w0) + dotS1 w0 -> afg[0])
  computeH(0);
  buildDot(IC<1>{}, 0, 0);
  asm volatile("s_waitcnt lgkmcnt(0)" ::: "memory");
  __builtin_amdgcn_s_barrier();

  // 32 steps: t<24 window phase (per window: dotS1, dotS2, h-double); t>=24 gfcopy.
  auto stepfn = [&](auto TC) {
    constexpr int t = decltype(TC)::value;
    constexpr int u = t + 1;
    // ---- build next A-chunk (u==24 deferred until after the t==23 fold) ----
    if constexpr (u < 24) {
      constexpr int r3 = u % 3, w = u / 3;
      if constexpr (r3 == 0)      { computeH(w); buildDot(IC<1>{}, w, u & 1); }
      else if constexpr (r3 == 1) buildDot(IC<2>{}, u / 3, u & 1);
      else                        buildH(u & 1);
    } else if constexpr (u >= 25 && u < 32) {
      gfcopy(IC<u - 24>{}, u & 1);
    }
    // ---- MFMA current chunk(s) ----
    if constexpr (t < 24) {
      constexpr int g = t / 3, r3 = t % 3;
      if constexpr (r3 < 2) {
        constexpr int q = 4 * g + r3;
        mfma_into(accG, t & 1, &Bl[q & 3][wc * 2048 + fr * 32 + bswz]);
      } else {
        constexpr int q = 4 * g + 2;
        mfma_into(accG, t & 1, &Bl[q & 3][wc * 2048 + fr * 32 + bswz]);        // h @ W'
        mfma_into(accA, t & 1, &Bl[(q + 1) & 3][wc * 2048 + fr * 32 + bswz]);  // h @ WgH
      }
    } else {
      constexpr int q = t + 8;
      mfma_into(accA, t & 1, &Bl[q & 3][wc * 2048 + fr * 32 + bswz]);          // gf @ WgGF
    }
    if constexpr (t == 23) {          // GEMM1 complete: fold accG -> packed bf16 g_feat
      #pragma unroll
      for (int nt = 0; nt < 4; ++nt)
        #pragma unroll
        for (int ai = 0; ai < 2; ++ai) {
          f32x4 a = accG[ai][nt];
          gfp[ai][nt][0] = pkbf(a[0] + pbv[nt], a[1] + pbv[nt]);
          gfp[ai][nt][1] = pkbf(a[2] + pbv[nt], a[3] + pbv[nt]);
        }
      gfcopy(IC<0>{}, 0);             // build for step 24 (after fold)
    }
    // ---- stage chunks for step t+2; counted wait keeps them flying ----
    if constexpr (t + 2 < 32) {
      constexpr int s2 = t + 2;
      constexpr int nq = (s2 < 24) ? ((s2 % 3 == 2) ? 2 : 1) : 1;
      constexpr int q0 = (s2 < 24) ? (4 * (s2 / 3) + s2 % 3) : (s2 + 8);
      stageQ(IC<q0>{});
      if constexpr (nq == 2) {
        stageQ(IC<q0 + 1>{});
        asm volatile("s_waitcnt vmcnt(4) lgkmcnt(0)" ::: "memory");
      } else {
        asm volatile("s_waitcnt vmcnt(2) lgkmcnt(0)" ::: "memory");
      }
    } else {
      asm volatile("s_waitcnt vmcnt(0) lgkmcnt(0)" ::: "memory");
    }
    __builtin_amdgcn_s_barrier();
  };
  auto run8 = [&](auto B8) {
    constexpr int b8 = decltype(B8)::value;
    stepfn(IC<b8 + 0>{}); stepfn(IC<b8 + 1>{}); stepfn(IC<b8 + 2>{}); stepfn(IC<b8 + 3>{});
    stepfn(IC<b8 + 4>{}); stepfn(IC<b8 + 5>{}); stepfn(IC<b8 + 6>{}); stepfn(IC<b8 + 7>{});
  };
  run8(IC<0>{}); run8(IC<8>{}); run8(IC<16>{}); run8(IC<24>{});

  // ---- final epilogue: alpha, silu, LayerScale, residual (h recomputed from x) ----
  float gbv[4], gmv[4];
  #pragma unroll
  for (int nt = 0; nt < 4; ++nt) {
    int col = wc * 64 + nt * 16 + fr;
    gbv[nt] = gbias[col]; gmv[nt] = gamma[col];
  }
  #pragma unroll
  for (int ai = 0; ai < 2; ++ai)
    #pragma unroll
    for (int rr = 0; rr < 4; ++rr) {
      const int row = wr * 32 + ai * 16 + kq * 4 + rr;
      const long pix = pix0 + row;
      const float mu2 = mursh[row * 2], rs2 = mursh[row * 2 + 1];
      #pragma unroll
      for (int nt = 0; nt < 4; ++nt) {
        int col = wc * 64 + nt * 16 + fr;
        float xv = x[pix * 256 + col];
        float hh = (xv - mu2) * rs2 * gshb[0][col] + gshb[1][col];
        u32 pw = gfp[ai][nt][rr >> 1];
        float gfv = bfu2f((u16)((rr & 1) ? (pw >> 16) : pw));
        float al = fsigmoid(accA[ai][nt][rr] + gbv[nt]);
        out[pix * 256 + col] = xv + (fsilu(hh) + al * gfv) * gmv[nt];
      }
    }
}

extern "C" void kernel_launch(void* const* d_in, const int* in_sizes, int n_in,
                              void* d_out, int out_size, void* d_ws, size_t ws_size,
                              hipStream_t stream) {
  const float* x     = (const float*)d_in[0];
  const float* lng   = (const float*)d_in[1];
  const float* lnb   = (const float*)d_in[2];
  const float* pk    = (const float*)d_in[3];
  const float* pbias = (const float*)d_in[4];
  const float* gk    = (const float*)d_in[5];
  const float* gbias = (const float*)d_in[6];
  const float* gamma = (const float*)d_in[7];
  float* out = (float*)d_out;

  char* ws = (char*)d_ws;
  u16*   wsdot   = (u16*)ws;                       // 262144 B (16 chunks)
  u16*   wsgate  = (u16*)(ws + 262144);            // 262144 B (16 chunks: 8 WgH + 8 WgGF)
  float* meang   = (float*)(ws + 524288);          // 8256 B
  u16*   wsW     = (u16*)(ws + 532544);            // 1048576 B (per-batch W')
  float* partial = (float*)(ws + 532544);          // 786432 B — dead before wfold writes W'
  float* mu_rs   = (float*)(ws + 1581120);         // 589824 B (total ~2.07 MB)

  wconv<<<128, 256, 0, stream>>>(pk, gk, wsdot, wsgate);
  prep<<<768, 256, 0, stream>>>(x, lng, lnb, mu_rs, partial);
  ln_mean<<<8, 256, 0, stream>>>(partial, meang);
  wfold<<<256, 256, 0, stream>>>(pk, meang, wsW);
  fused<<<NPIX / MROW, 512, 0, stream>>>(x, lng, lnb, wsdot, wsW, wsgate, mu_rs,
                                         pbias, gbias, gamma, meang, out);
}

// Round 15
// 138.437 us; speedup vs baseline: 1.1846x; 1.1846x over previous
//
#include <hip/hip_runtime.h>
#include <hip/hip_bf16.h>

typedef unsigned short u16;
typedef unsigned int   u32;
typedef __attribute__((ext_vector_type(2))) float f32x2;
typedef __attribute__((ext_vector_type(4))) float f32x4;
typedef __attribute__((ext_vector_type(4))) u32   u32x4;
typedef __attribute__((ext_vector_type(8))) short bf16x8;

#define HWPIX  9216
#define NPIX   73728
#define LN_EPS 1e-5f
#define MROW   64       // pixels per block
#define ASTR   40       // afg chunk row stride (elems): 32 + 8 pad

template<int N> struct IC { static constexpr int value = N; };

__device__ __forceinline__ u16 f2bf(float f){
  u32 u = __builtin_bit_cast(u32, f);
  u += 0x7fffu + ((u >> 16) & 1u);          // RTNE
  return (u16)(u >> 16);
}
__device__ __forceinline__ u32 pkbf(float lo, float hi){   // 1 inst packed cvt
  u32 d;
  asm("v_cvt_pk_bf16_f32 %0, %1, %2" : "=v"(d) : "v"(lo), "v"(hi));
  return d;
}
__device__ __forceinline__ float bfu2f(u16 h){ return __builtin_bit_cast(float, (u32)h << 16); }
__device__ __forceinline__ float fsigmoid(float v){ return __fdividef(1.f, 1.f + __expf(-v)); }
__device__ __forceinline__ float fsilu(float v){ return __fdividef(v, 1.f + __expf(-v)); }

__device__ __forceinline__ void gld16(const u16* g, u16* l){
  __builtin_amdgcn_global_load_lds((const __attribute__((address_space(1))) void*)g,
                                   (__attribute__((address_space(3))) void*)l,
                                   16, 0, 0);
}

// ---------------- kernel 1: weight convert (r14-validated layout) ------------------
// wsdot chunk t<16: window w=t>>1, shift s=(t&1)+1 (s1=pk rows 0..255, s2=rows 512..767).
// wsgate chunks 0..7 = WgH (gk rows 0..255), 8..15 = WgGF (gk rows 256..511).
__global__ __launch_bounds__(256) void wconv(const float* __restrict__ pk,
                                             const float* __restrict__ gk,
                                             u16* __restrict__ wsdot,
                                             u16* __restrict__ wsgate)
{
  int gid = blockIdx.x * 256 + threadIdx.x;   // 32768 = 128 blocks
  int t = gid >> 10, S = gid & 1023;
  int q = (S >> 2) & 15, pp = S & 3, w8 = (S >> 6) & 7, rb = S >> 9;
  int n  = rb * 128 + w8 * 16 + q;
  int kq = pp ^ ((q >> 1) & 3);
  const float* W; int k0; u16* dst;
  if (t < 16) { W = pk; k0 = (t & 1) * 512 + (t >> 1) * 32 + kq * 8; dst = wsdot + (size_t)t * 8192; }
  else        { W = gk; k0 = (t - 16) * 32 + kq * 8;                 dst = wsgate + (size_t)(t - 16) * 8192; }
  u32 ow[4];
  #pragma unroll
  for (int e = 0; e < 4; ++e) {
    float f0 = W[(size_t)(k0 + 2*e)     * 256 + n];
    float f1 = W[(size_t)(k0 + 2*e + 1) * 256 + n];
    ow[e] = (u32)f2bf(f0) | ((u32)f2bf(f1) << 16);
  }
  *(u32x4*)(dst + (size_t)S * 8) = (u32x4){ow[0], ow[1], ow[2], ow[3]};
}

// ---------------- kernel 2: per-pixel LN stats + per-(b,h) partial sums ------------
__global__ __launch_bounds__(256) void prep(const float* __restrict__ x,
                                            const float* __restrict__ g,
                                            const float* __restrict__ bt,
                                            float* __restrict__ mu_rs,
                                            float* __restrict__ partial)
{
  const int bh = blockIdx.x;
  const int tid = threadIdx.x;
  const int wv = tid >> 6, lane = tid & 63;
  const float* xrow = x + (size_t)bh * 96 * 256;
  __shared__ float red[4][256];

  f32x4 gv = *(const f32x4*)(g  + lane * 4);
  f32x4 bv = *(const f32x4*)(bt + lane * 4);
  f32x4 acc = {0.f, 0.f, 0.f, 0.f};

  for (int w = wv; w < 96; w += 4) {
    f32x4 v = *(const f32x4*)(xrow + w * 256 + lane * 4);
    float s  = v[0] + v[1] + v[2] + v[3];
    float s2 = v[0]*v[0] + v[1]*v[1] + v[2]*v[2] + v[3]*v[3];
    #pragma unroll
    for (int m = 1; m < 64; m <<= 1) { s += __shfl_xor(s, m); s2 += __shfl_xor(s2, m); }
    float mu  = s * (1.f / 256.f);
    float var = s2 * (1.f / 256.f) - mu * mu;
    float rs  = rsqrtf(var + LN_EPS);
    if (lane == 0) *(f32x2*)(mu_rs + (size_t)(bh * 96 + w) * 2) = f32x2{mu, rs};
    #pragma unroll
    for (int j = 0; j < 4; ++j) acc[j] += (v[j] - mu) * rs * gv[j] + bv[j];
  }
  *(f32x4*)(&red[wv][lane * 4]) = acc;
  __syncthreads();
  float s = red[0][tid] + red[1][tid] + red[2][tid] + red[3][tid];
  partial[(size_t)bh * 256 + tid] = s;
}

// ---------------- kernel 3: reduce rows -> spatial mean [8][258] (wrap-padded) -----
__global__ __launch_bounds__(256) void ln_mean(const float* __restrict__ partial,
                                               float* __restrict__ mean)
{
  int b = blockIdx.x, c = threadIdx.x;
  float s = 0.f;
  for (int h = 0; h < 96; ++h) s += partial[((size_t)b * 96 + h) * 256 + c];
  float m = s * (1.f / 9216.f);
  mean[b * 258 + c] = m;
  if (c < 2) mean[b * 258 + 256 + c] = m;
}

// ---------------- kernel 4: fold wedge into per-batch weights (r14-validated) ------
__global__ __launch_bounds__(256) void wfold(const float* __restrict__ pk,
                                             const float* __restrict__ meang,
                                             u16* __restrict__ wsW)
{
  __shared__ float msh[256];
  int gid = blockIdx.x * 256 + threadIdx.x;   // 65536 = 256 blocks
  int chunk = gid >> 10;
  int b = chunk >> 3, j = chunk & 7;
  msh[threadIdx.x] = meang[b * 258 + threadIdx.x];
  __syncthreads();
  int S = gid & 1023;
  int q = (S >> 2) & 15, pp = S & 3, w8 = (S >> 6) & 7, rb = S >> 9;
  int n  = rb * 128 + w8 * 16 + q;
  int kq = pp ^ ((q >> 1) & 3);
  u32 ow[4];
  #pragma unroll
  for (int e = 0; e < 4; ++e) {
    float r[2];
    #pragma unroll
    for (int hh = 0; hh < 2; ++hh) {
      int c = j * 32 + kq * 8 + 2 * e + hh;
      int cm1 = (c + 255) & 255, cm2 = (c + 254) & 255;
      int cp1 = (c + 1) & 255,   cp2 = (c + 2) & 255;
      r[hh] = msh[cm1] * pk[(size_t)(256 + cm1) * 256 + n]
            - msh[cp1] * pk[(size_t)(256 + c)   * 256 + n]
            + msh[cm2] * pk[(size_t)(768 + cm2) * 256 + n]
            - msh[cp2] * pk[(size_t)(768 + c)   * 256 + n];
    }
    ow[e] = (u32)f2bf(r[0]) | ((u32)f2bf(r[1]) << 16);
  }
  *(u32x4*)(wsW + (size_t)chunk * 8192 + (size_t)S * 8) = (u32x4){ow[0], ow[1], ow[2], ow[3]};
}

// ---------------- kernel 5: fused main ---------------------------------------------
// r13 resources (depth-3 ring, 63.5KB LDS, uniform 1 chunk/step, 40 steps) + r14's
// sharing via SEQUENTIAL pairs: dots {s1w,s2w} share one computeH6; seg2/3 pairs
// {h@W'(w), h@WgH(w)} share one afg chunk (pair-parity dbuf) + one computeH4.
// accA joins only for steps>=17; peak regs ~124 (<=128 for 2 blocks/CU).
__global__ __launch_bounds__(512, 2) void fused(
    const float* __restrict__ x,
    const float* __restrict__ lng, const float* __restrict__ lnb,
    const u16* __restrict__ wsdot, const u16* __restrict__ wsW,
    const u16* __restrict__ wsgate, const float* __restrict__ mu_rs,
    const float* __restrict__ pbias, const float* __restrict__ gbias,
    const float* __restrict__ gamma, const float* __restrict__ meang,
    float* __restrict__ out)
{
  __shared__ u16 afg[2][MROW * ASTR];   // 10240 B
  __shared__ u16 Bl [3][8192];          // 49152 B
  __shared__ float gshb[2][260];        //  2080 B
  __shared__ float msh[258];            //  1032 B
  __shared__ float mursh[128];          //   512 B   (total 63016 B)

  const int tid  = threadIdx.x;
  const long pix0 = (long)blockIdx.x * MROW;
  const int bat  = (int)(pix0 / HWPIX);      // 9216 % 64 == 0

  const int wave = tid >> 6, lane = tid & 63;
  const int wr = wave & 1, wc = wave >> 1;       // 2x4 wave grid
  const int fr = lane & 15, kq = lane >> 4;
  const int bswz = (kq ^ ((fr >> 1) & 3)) * 8;
  const int brow = tid >> 3, o4 = (tid & 7) * 4; // A-build: row, 4-ch slice

  // chunk stream q: 0..15 dots {s1w,s2w}; 16..31 pairs {W'(w), WgH(w)}; 32..39 WgGF.
  auto stageQ = [&](auto QC) {
    constexpr int q  = decltype(QC)::value;
    constexpr int sl = q % 3;
    const u16* base;
    if constexpr (q < 16) {
      base = wsdot + (size_t)q * 8192;
    } else if constexpr (q < 32) {
      constexpr int p = q - 16, w = p >> 1;
      if constexpr ((p & 1) == 0) base = wsW + (size_t)bat * 65536 + (size_t)w * 8192;
      else                        base = wsgate + (size_t)w * 8192;
    } else {
      base = wsgate + (size_t)(q - 24) * 8192;   // WgGF chunks 8..15
    }
    const u16* src = base + tid * 8;
    u16* dst = &Bl[sl][wave * 512];              // wave-uniform base; HW adds lane*16B
    gld16(src, dst);
    gld16(src + 4096, dst + 4096);
  };

  stageQ(IC<0>{});
  stageQ(IC<1>{});

  // ---- table fill ----
  if (tid < 256)      { gshb[0][tid] = lng[tid]; gshb[1][tid] = lnb[tid]; }
  else if (tid < 260) { int c = tid - 256; gshb[0][256 + c] = lng[c]; gshb[1][256 + c] = lnb[c]; }
  if (tid < 258) msh[tid] = meang[bat * 258 + tid];
  if (tid < 128) mursh[tid] = mu_rs[pix0 * 2 + tid];

  f32x4 accG[2][4], accA[2][4];
  #pragma unroll
  for (int i = 0; i < 2; ++i)
    #pragma unroll
    for (int j = 0; j < 4; ++j) { accG[i][j] = (f32x4){0,0,0,0}; accA[i][j] = (f32x4){0,0,0,0}; }
  u32 gfp[2][4][2];

  __syncthreads();                    // tables + stage(0,1) drained (prologue only)

  const float* xrowp = x + (pix0 + brow) * 256;
  const float muv = mursh[brow * 2];
  const float rsv = mursh[brow * 2 + 1];

  // h window registers: shared across pair builds
  float h0, h1, h2, h3, h4, h5;
  auto computeH6 = [&](int w) {       // h0..h5 (dots need +5 lookahead)
    const int cc = w * 32 + o4;
    f32x4 xa = *(const f32x4*)(xrowp + cc);
    f32x2 xb = (cc == 252) ? f32x2{xrowp[0], xrowp[1]}
                           : *(const f32x2*)(xrowp + cc + 4);
    h0 = (xa[0] - muv) * rsv * gshb[0][cc]     + gshb[1][cc];
    h1 = (xa[1] - muv) * rsv * gshb[0][cc + 1] + gshb[1][cc + 1];
    h2 = (xa[2] - muv) * rsv * gshb[0][cc + 2] + gshb[1][cc + 2];
    h3 = (xa[3] - muv) * rsv * gshb[0][cc + 3] + gshb[1][cc + 3];
    h4 = (xb[0] - muv) * rsv * gshb[0][cc + 4] + gshb[1][cc + 4];
    h5 = (xb[1] - muv) * rsv * gshb[0][cc + 5] + gshb[1][cc + 5];
  };
  auto computeH4 = [&](int w) {       // h0..h3 only (plain-h chunks)
    const int cc = w * 32 + o4;
    f32x4 xa = *(const f32x4*)(xrowp + cc);
    h0 = (xa[0] - muv) * rsv * gshb[0][cc]     + gshb[1][cc];
    h1 = (xa[1] - muv) * rsv * gshb[0][cc + 1] + gshb[1][cc + 1];
    h2 = (xa[2] - muv) * rsv * gshb[0][cc + 2] + gshb[1][cc + 2];
    h3 = (xa[3] - muv) * rsv * gshb[0][cc + 3] + gshb[1][cc + 3];
  };
  auto buildDot = [&](auto SC, int w, int buf) {
    constexpr int s = decltype(SC)::value;
    const int cc = w * 32 + o4;
    float a0, a1, a2, a3;
    if constexpr (s == 1) { a0 = h1; a1 = h2; a2 = h3; a3 = h4; }
    else                  { a0 = h2; a1 = h3; a2 = h4; a3 = h5; }
    float r0 = fsilu(h0 * (a0 - msh[cc + s]));
    float r1 = fsilu(h1 * (a1 - msh[cc + 1 + s]));
    float r2 = fsilu(h2 * (a2 - msh[cc + 2 + s]));
    float r3 = fsilu(h3 * (a3 - msh[cc + 3 + s]));
    *(u32*)(&afg[buf][brow * ASTR + o4])     = pkbf(r0, r1);
    *(u32*)(&afg[buf][brow * ASTR + o4 + 2]) = pkbf(r2, r3);
  };
  auto buildH = [&](int buf) {
    *(u32*)(&afg[buf][brow * ASTR + o4])     = pkbf(h0, h1);
    *(u32*)(&afg[buf][brow * ASTR + o4 + 2]) = pkbf(h2, h3);
  };
  auto gfcopy = [&](auto CGC, int buf) {
    constexpr int cg = decltype(CGC)::value;
    constexpr int par = cg & 1;
    if (wc == (cg >> 1)) {
      #pragma unroll
      for (int v = 0; v < 2; ++v) {
        #pragma unroll
        for (int ai = 0; ai < 2; ++ai)
          #pragma unroll
          for (int rp = 0; rp < 2; ++rp) {
            u32 pw = gfp[ai][par * 2 + v][rp];
            int row0 = wr * 32 + ai * 16 + kq * 4 + rp * 2;
            afg[buf][row0 * ASTR + v * 16 + fr]       = (u16)pw;
            afg[buf][(row0 + 1) * ASTR + v * 16 + fr] = (u16)(pw >> 16);
          }
      }
    }
  };

  auto mfma_into = [&](f32x4 (&ac)[2][4], int abuf, int sl) {
    const u16* ar = &afg[abuf][(wr * 32 + fr) * ASTR + kq * 8];
    bf16x8 av0 = *(const bf16x8*)(ar);
    bf16x8 av1 = *(const bf16x8*)(ar + 16 * ASTR);
    const u16* bp = &Bl[sl][wc * 2048 + fr * 32 + bswz];
    __builtin_amdgcn_s_setprio(1);
    #pragma unroll
    for (int nt = 0; nt < 4; ++nt) {
      bf16x8 bv = *(const bf16x8*)(bp + nt * 512);
      ac[0][nt] = __builtin_amdgcn_mfma_f32_16x16x32_bf16(av0, bv, ac[0][nt], 0, 0, 0);
      ac[1][nt] = __builtin_amdgcn_mfma_f32_16x16x32_bf16(av1, bv, ac[1][nt], 0, 0, 0);
    }
    __builtin_amdgcn_s_setprio(0);
  };

  // prologue: build chunk 0 (dot s1 w0; h(w0) persists into step 0's s2 build)
  computeH6(0);
  buildDot(IC<1>{}, 0, 0);
  asm volatile("s_waitcnt lgkmcnt(0)" ::: "memory");
  __builtin_amdgcn_s_barrier();

  auto stepfn = [&](auto TC) {
    constexpr int t = decltype(TC)::value;
    constexpr int u = t + 1;
    // ---- build next A-chunk ----
    if constexpr (u < 16) {
      constexpr int w = u >> 1;
      if constexpr ((u & 1) == 0) { computeH6(w); buildDot(IC<1>{}, w, u & 1); }
      else                        buildDot(IC<2>{}, w, u & 1);
    } else if constexpr (u >= 16 && u < 32) {
      // pair p=(u-16)>>1's shared h-chunk built at even (u-16): one build per pair
      if constexpr (((u - 16) & 1) == 0) {
        constexpr int p = (u - 16) >> 1;
        computeH4(p);
        buildH(p & 1);
      }
    } else if constexpr (u >= 33 && u < 40) {
      gfcopy(IC<u - 32>{}, u & 1);
    }
    // ---- MFMA current chunk ----
    if constexpr (t < 16) {
      mfma_into(accG, t & 1, t % 3);
    } else if constexpr (t < 32) {
      constexpr int p = (t - 16) >> 1;
      if constexpr (((t - 16) & 1) == 0) mfma_into(accG, p & 1, t % 3);   // h @ W'
      else                               mfma_into(accA, p & 1, t % 3);   // h @ WgH
    } else {
      mfma_into(accA, t & 1, t % 3);                                      // gf @ WgGF
    }
    if constexpr (t == 31) {          // GEMM1 complete: fold accG -> packed bf16 g_feat
      #pragma unroll
      for (int nt = 0; nt < 4; ++nt) {
        float pb = pbias[wc * 64 + nt * 16 + fr];
        #pragma unroll
        for (int ai = 0; ai < 2; ++ai) {
          f32x4 a = accG[ai][nt];
          gfp[ai][nt][0] = pkbf(a[0] + pb, a[1] + pb);
          gfp[ai][nt][1] = pkbf(a[2] + pb, a[3] + pb);
        }
      }
      gfcopy(IC<0>{}, 0);             // gf chunk 0 for step 32
    }
    // ---- stage chunk t+2 into ring; counted drain keeps newest flying ----
    if constexpr (t + 2 < 40) stageQ(IC<t + 2>{});
    if constexpr (t < 37) asm volatile("s_waitcnt vmcnt(2) lgkmcnt(0)" ::: "memory");
    else                  asm volatile("s_waitcnt vmcnt(0) lgkmcnt(0)" ::: "memory");
    __builtin_amdgcn_s_barrier();
  };
  auto run8 = [&](auto B8) {
    constexpr int b8 = decltype(B8)::value;
    stepfn(IC<b8 + 0>{}); stepfn(IC<b8 + 1>{}); stepfn(IC<b8 + 2>{}); stepfn(IC<b8 + 3>{});
    stepfn(IC<b8 + 4>{}); stepfn(IC<b8 + 5>{}); stepfn(IC<b8 + 6>{}); stepfn(IC<b8 + 7>{});
  };
  run8(IC<0>{}); run8(IC<8>{}); run8(IC<16>{}); run8(IC<24>{}); run8(IC<32>{});

  // ---- final epilogue: alpha, silu, LayerScale, residual (h recomputed from x) ----
  float gbv[4], gmv[4];
  #pragma unroll
  for (int nt = 0; nt < 4; ++nt) {
    int col = wc * 64 + nt * 16 + fr;
    gbv[nt] = gbias[col]; gmv[nt] = gamma[col];
  }
  #pragma unroll
  for (int ai = 0; ai < 2; ++ai)
    #pragma unroll
    for (int rr = 0; rr < 4; ++rr) {
      const int row = wr * 32 + ai * 16 + kq * 4 + rr;
      const long pix = pix0 + row;
      const float mu2 = mursh[row * 2], rs2 = mursh[row * 2 + 1];
      #pragma unroll
      for (int nt = 0; nt < 4; ++nt) {
        int col = wc * 64 + nt * 16 + fr;
        float xv = x[pix * 256 + col];
        float hh = (xv - mu2) * rs2 * gshb[0][col] + gshb[1][col];
        u32 pw = gfp[ai][nt][rr >> 1];
        float gfv = bfu2f((u16)((rr & 1) ? (pw >> 16) : pw));
        float al = fsigmoid(accA[ai][nt][rr] + gbv[nt]);
        out[pix * 256 + col] = xv + (fsilu(hh) + al * gfv) * gmv[nt];
      }
    }
}

extern "C" void kernel_launch(void* const* d_in, const int* in_sizes, int n_in,
                              void* d_out, int out_size, void* d_ws, size_t ws_size,
                              hipStream_t stream) {
  const float* x     = (const float*)d_in[0];
  const float* lng   = (const float*)d_in[1];
  const float* lnb   = (const float*)d_in[2];
  const float* pk    = (const float*)d_in[3];
  const float* pbias = (const float*)d_in[4];
  const float* gk    = (const float*)d_in[5];
  const float* gbias = (const float*)d_in[6];
  const float* gamma = (const float*)d_in[7];
  float* out = (float*)d_out;

  char* ws = (char*)d_ws;
  u16*   wsdot   = (u16*)ws;                       // 262144 B
  u16*   wsgate  = (u16*)(ws + 262144);            // 262144 B (8 WgH + 8 WgGF)
  float* meang   = (float*)(ws + 524288);          // 8256 B
  u16*   wsW     = (u16*)(ws + 532544);            // 1048576 B (per-batch W')
  float* partial = (float*)(ws + 532544);          // 786432 B — dead before wfold writes W'
  float* mu_rs   = (float*)(ws + 1581120);         // 589824 B (total ~2.07 MB)

  wconv<<<128, 256, 0, stream>>>(pk, gk, wsdot, wsgate);
  prep<<<768, 256, 0, stream>>>(x, lng, lnb, mu_rs, partial);
  ln_mean<<<8, 256, 0, stream>>>(partial, meang);
  wfold<<<256, 256, 0, stream>>>(pk, meang, wsW);
  fused<<<NPIX / MROW, 512, 0, stream>>>(x, lng, lnb, wsdot, wsW, wsgate, mu_rs,
                                         pbias, gbias, gamma, meang, out);
}